// Round 4
// baseline (101.191 us; speedup 1.0000x reference)
//
#include <hip/hip_runtime.h>
#include <cstdint>
#include <cstddef>

typedef unsigned short u16;
typedef __attribute__((ext_vector_type(8))) short short8;
typedef __attribute__((ext_vector_type(4))) float f32x4;

__device__ __forceinline__ u16 f2bf(float f){
  union { float f; unsigned u; } c; c.f = f;
  unsigned u = c.u;
  u += 0x7fffu + ((u >> 16) & 1u);   // RNE
  return (u16)(u >> 16);
}
__device__ __forceinline__ unsigned pk2(float a, float b){
  union { float f; unsigned u; } ca, cb; ca.f = a; cb.f = b;
  return ((ca.u + 0x8000u) >> 16) | ((cb.u + 0x8000u) & 0xFFFF0000u);
}

// ---------------------------------------------------------------------------
// Kernel 1: transpose x [b][128ci][4096pos] fp32 -> xT [b][4096pos][128ci] bf16
//           + per-(b,chunk,ci) partial sums for SE pool.
// 1D grid 512, b = bid&15 so xT[b] lines are written from XCD b%8 (bid%8==b%8)
// -> conv's reads (same XCD) are local-L2 hits.
// ---------------------------------------------------------------------------
__global__ __launch_bounds__(256) void xpose_pool(
    const float* __restrict__ x, u16* __restrict__ xT, float* __restrict__ part)
{
  const int bid = blockIdx.x;
  const int b = bid & 15, chunk = bid >> 4;
  const int pos0 = chunk << 7;
  const int tid = threadIdx.x;
  __shared__ u16 tile[16384];        // 32 KB, swizzled [row][g'][8ci]
  __shared__ float psum[128 * 33];
  const float* xb = x + ((size_t)b << 19) + pos0;
  const int p4 = (tid & 31) << 2;
  const int swz = (tid & 31) & 7;

  #pragma unroll
  for (int i = 0; i < 2; ++i){
    const int gci = (tid >> 5) + (i << 3);
    const int ci8 = gci << 3;
    float4 L[8];
    #pragma unroll
    for (int j = 0; j < 8; ++j)
      L[j] = *(const float4*)(xb + ((size_t)(ci8 + j) << 12) + p4);
    #pragma unroll
    for (int j = 0; j < 8; ++j)
      psum[(ci8 + j) * 33 + (tid & 31)] = L[j].x + L[j].y + L[j].z + L[j].w;
    const int gs = gci ^ swz;
    const float* e = (const float*)L;
    #pragma unroll
    for (int p = 0; p < 4; ++p){
      const int row = p4 + p;
      uint4 V;
      V.x = pk2(e[0 * 4 + p], e[1 * 4 + p]);
      V.y = pk2(e[2 * 4 + p], e[3 * 4 + p]);
      V.z = pk2(e[4 * 4 + p], e[5 * 4 + p]);
      V.w = pk2(e[6 * 4 + p], e[7 * 4 + p]);
      *(uint4*)(tile + (row << 7) + (gs << 3)) = V;
    }
  }
  __syncthreads();

  if (tid < 128){
    float s = 0.f;
    #pragma unroll 8
    for (int j = 0; j < 32; ++j) s += psum[tid * 33 + j];
    part[((b << 5) + chunk) * 128 + tid] = s;
  }

  u16* xo = xT + ((((size_t)b << 12) + pos0) << 7);
  const int g = tid & 15, rb = (tid >> 4) << 3;
  #pragma unroll
  for (int r = 0; r < 8; ++r){
    const int row = rb + r;
    const int gs = g ^ ((row >> 2) & 7);
    uint4 v = *(const uint4*)(tile + (row << 7) + (gs << 3));
    *(uint4*)(xo + ((size_t)row << 7) + (g << 3)) = v;
  }
}

// ---------------------------------------------------------------------------
// Kernel 2: finish pooling, SE MLP, softmax(logits/30) -> attn[16][4]
// ---------------------------------------------------------------------------
__global__ void attn_fc(const float* __restrict__ part, const float* __restrict__ w1,
                        const float* __restrict__ w2, const float* __restrict__ b2,
                        float* __restrict__ attn)
{
  const int b = blockIdx.x, t = threadIdx.x;
  __shared__ float sp[128];
  __shared__ float sh[33];
  __shared__ float sl[4];
  const float* pb = part + (b << 12);
  float s = 0.f;
  for (int c = 0; c < 32; ++c) s += pb[(c << 7) + t];
  sp[t] = s * (1.f / 4096.f);
  __syncthreads();
  if (t < 33){
    float h = 0.f;
    for (int ci = 0; ci < 128; ++ci) h += sp[ci] * w1[t * 128 + ci];
    sh[t] = fmaxf(h, 0.f);
  }
  __syncthreads();
  if (t < 4){
    float l = b2[t];
    for (int j = 0; j < 33; ++j) l += sh[j] * w2[t * 33 + j];
    sl[t] = l * (1.f / 30.f);
  }
  __syncthreads();
  if (t == 0){
    float m = fmaxf(fmaxf(sl[0], sl[1]), fmaxf(sl[2], sl[3]));
    float e0 = __expf(sl[0] - m), e1 = __expf(sl[1] - m);
    float e2 = __expf(sl[2] - m), e3 = __expf(sl[3] - m);
    float inv = 1.f / (e0 + e1 + e2 + e3);
    attn[(b << 2) + 0] = e0 * inv; attn[(b << 2) + 1] = e1 * inv;
    attn[(b << 2) + 2] = e2 * inv; attn[(b << 2) + 3] = e3 * inv;
  }
}

// ---------------------------------------------------------------------------
// Kernel 3: wcomb[b][tap][co][ci] = sum_k attn[b][k]*W[k*128+co][ci][tap] (bf16)
// grid 128: bid = g*16 + b  (g = co-group 0..7, 16 co each). Since 16%8==0,
// bid%8 == b%8 -> wcomb[b] dirty lines live in XCD b%8's L2 = conv's XCD.
// ---------------------------------------------------------------------------
__global__ __launch_bounds__(256) void combine(
    const float* __restrict__ W, const float* __restrict__ bias,
    const float* __restrict__ attn, u16* __restrict__ wcomb,
    float* __restrict__ bcomb)
{
  const int bid = blockIdx.x;
  const int b = bid & 15, g = bid >> 4;
  const int tid = threadIdx.x;
  __shared__ float wk[4][1152];
  __shared__ float sat[4];
  if (tid < 4) sat[tid] = attn[(b << 2) + tid];
  __syncthreads();
  const float a0 = sat[0], a1 = sat[1], a2 = sat[2], a3 = sat[3];
  if (tid < 16){
    const int co = (g << 4) + tid;
    bcomb[(b << 7) + co] = a0 * bias[co] + a1 * bias[128 + co]
                         + a2 * bias[256 + co] + a3 * bias[384 + co];
  }
  u16* wob = wcomb + (size_t)b * 147456;
  for (int c16 = 0; c16 < 16; ++c16){
    const int co = (g << 4) + c16;
    __syncthreads();   // prior iter done reading wk
    for (int idx = tid; idx < 4608; idx += 256){
      int k = idx / 1152, j = idx - k * 1152;
      wk[k][j] = W[(size_t)(k * 128 + co) * 1152 + j];
    }
    __syncthreads();
    for (int r = tid; r < 1152; r += 256){
      int tap = r >> 7, ci = r & 127;
      int j = ci * 9 + tap;
      float s = a0 * wk[0][j] + a1 * wk[1][j] + a2 * wk[2][j] + a3 * wk[3][j];
      wob[tap * 16384 + (co << 7) + ci] = f2bf(s);
    }
  }
}

// ---------------------------------------------------------------------------
// Kernel 4 (v4): 9-tap implicit GEMM, bf16 MFMA 16x16x32, barrier-free main
// loop, fully-unrolled 36-step (tap,kc) software pipeline:
//   A (weights, global, local-L2-homed) prefetched 2 steps ahead (3 bufs),
//   B (x, LDS) prefetched 1 step ahead (2 bufs). All indices compile-time.
// LDS: x-tile [4 rows][16 oct][66 cols][8ci] = 67584 B -> 2 blocks/CU.
// grid 512 x 256 thr (4 waves: wr=row, wc=co-half); b homed to XCD b%8.
// ---------------------------------------------------------------------------
__global__ __launch_bounds__(256, 2) void conv_mfma(
    const u16* __restrict__ xT, const u16* __restrict__ wcomb,
    const float* __restrict__ bcomb, float* __restrict__ out)
{
  extern __shared__ char smem[];
  u16* s_xt = (u16*)smem;   // 4224 granules * 16B

  const int tid = threadIdx.x;
  const int lane = tid & 63, wid = tid >> 6;
  const int wr = wid & 1, wc = wid >> 1;
  const int l15 = lane & 15, hi = lane >> 4;

  const int bid = blockIdx.x;
  const int xcd = bid & 7, j = bid >> 3;
  const int b = ((j >> 5) << 3) | xcd;     // b % 8 == xcd  (L2 homing)
  const int h0 = (j & 31) << 1;            // 2 output rows per block

  // ---- stage x tile: rows h0-1..h0+2 (4), cols -1..64 (66), all 128 ci ----
  {
    const u16* xtb = xT + ((size_t)b << 19);
    for (int g = tid; g < 4224; g += 256){
      int oct = g & 15;
      int t = g >> 4;
      int col = t % 66;
      int row = t / 66;
      int h = h0 - 1 + row, w = col - 1;
      uint4 v = make_uint4(0u, 0u, 0u, 0u);
      if ((unsigned)h < 64u && (unsigned)w < 64u)
        v = *(const uint4*)(xtb + ((size_t)(((h << 6) + w) << 7) + (oct << 3)));
      *(uint4*)(s_xt + ((((row << 4) + oct) * 66 + col) << 3)) = v;
    }
  }
  __syncthreads();   // the ONLY barrier

  f32x4 acc[4][4] = {};
  short8 af[3][4];   // A frags, depth-2 prefetch (3 rotating bufs)
  short8 bf[2][4];   // B frags, depth-1 prefetch

  const u16* A0 = wcomb + (size_t)b * 147456 + (wc << 13) + l15 * 128 + (hi << 3);

#define LDA(P, S) { \
    const u16* _wt = A0 + ((S) >> 2) * 16384 + ((S) & 3) * 32; \
    af[P][0] = *(const short8*)(_wt); \
    af[P][1] = *(const short8*)(_wt + 2048); \
    af[P][2] = *(const short8*)(_wt + 4096); \
    af[P][3] = *(const short8*)(_wt + 6144); }

#define LDB(P, S) { \
    const int _tap = (S) >> 2, _kc = (S) & 3; \
    const int _dh = _tap / 3, _dw = _tap - 3 * _dh; \
    const u16* _bt = s_xt + (((wr + _dh) * 16 + _kc * 4 + hi) * 66 + l15 + _dw) * 8; \
    bf[P][0] = *(const short8*)(_bt); \
    bf[P][1] = *(const short8*)(_bt + 128); \
    bf[P][2] = *(const short8*)(_bt + 256); \
    bf[P][3] = *(const short8*)(_bt + 384); }

#define MM(PA, PB) { \
    acc[0][0] = __builtin_amdgcn_mfma_f32_16x16x32_bf16(af[PA][0], bf[PB][0], acc[0][0], 0, 0, 0); \
    acc[0][1] = __builtin_amdgcn_mfma_f32_16x16x32_bf16(af[PA][0], bf[PB][1], acc[0][1], 0, 0, 0); \
    acc[0][2] = __builtin_amdgcn_mfma_f32_16x16x32_bf16(af[PA][0], bf[PB][2], acc[0][2], 0, 0, 0); \
    acc[0][3] = __builtin_amdgcn_mfma_f32_16x16x32_bf16(af[PA][0], bf[PB][3], acc[0][3], 0, 0, 0); \
    acc[1][0] = __builtin_amdgcn_mfma_f32_16x16x32_bf16(af[PA][1], bf[PB][0], acc[1][0], 0, 0, 0); \
    acc[1][1] = __builtin_amdgcn_mfma_f32_16x16x32_bf16(af[PA][1], bf[PB][1], acc[1][1], 0, 0, 0); \
    acc[1][2] = __builtin_amdgcn_mfma_f32_16x16x32_bf16(af[PA][1], bf[PB][2], acc[1][2], 0, 0, 0); \
    acc[1][3] = __builtin_amdgcn_mfma_f32_16x16x32_bf16(af[PA][1], bf[PB][3], acc[1][3], 0, 0, 0); \
    acc[2][0] = __builtin_amdgcn_mfma_f32_16x16x32_bf16(af[PA][2], bf[PB][0], acc[2][0], 0, 0, 0); \
    acc[2][1] = __builtin_amdgcn_mfma_f32_16x16x32_bf16(af[PA][2], bf[PB][1], acc[2][1], 0, 0, 0); \
    acc[2][2] = __builtin_amdgcn_mfma_f32_16x16x32_bf16(af[PA][2], bf[PB][2], acc[2][2], 0, 0, 0); \
    acc[2][3] = __builtin_amdgcn_mfma_f32_16x16x32_bf16(af[PA][2], bf[PB][3], acc[2][3], 0, 0, 0); \
    acc[3][0] = __builtin_amdgcn_mfma_f32_16x16x32_bf16(af[PA][3], bf[PB][0], acc[3][0], 0, 0, 0); \
    acc[3][1] = __builtin_amdgcn_mfma_f32_16x16x32_bf16(af[PA][3], bf[PB][1], acc[3][1], 0, 0, 0); \
    acc[3][2] = __builtin_amdgcn_mfma_f32_16x16x32_bf16(af[PA][3], bf[PB][2], acc[3][2], 0, 0, 0); \
    acc[3][3] = __builtin_amdgcn_mfma_f32_16x16x32_bf16(af[PA][3], bf[PB][3], acc[3][3], 0, 0, 0); }

#define PIPE(S) { \
    if ((S) + 2 < 36) LDA((((S) + 2) % 3), ((S) + 2)); \
    if ((S) + 1 < 36) LDB((((S) + 1) & 1), ((S) + 1)); \
    MM(((S) % 3), ((S) & 1)); }

  LDA(0, 0); LDA(1, 1); LDB(0, 0);
  PIPE(0)  PIPE(1)  PIPE(2)  PIPE(3)  PIPE(4)  PIPE(5)
  PIPE(6)  PIPE(7)  PIPE(8)  PIPE(9)  PIPE(10) PIPE(11)
  PIPE(12) PIPE(13) PIPE(14) PIPE(15) PIPE(16) PIPE(17)
  PIPE(18) PIPE(19) PIPE(20) PIPE(21) PIPE(22) PIPE(23)
  PIPE(24) PIPE(25) PIPE(26) PIPE(27) PIPE(28) PIPE(29)
  PIPE(30) PIPE(31) PIPE(32) PIPE(33) PIPE(34) PIPE(35)

#undef PIPE
#undef MM
#undef LDB
#undef LDA

  // ---- epilogue: C/D layout col=lane&15 (pos), row=(lane>>4)*4+reg (co) ----
  const int h = h0 + wr;
  float* ob = out + ((size_t)b << 19);
  #pragma unroll
  for (int cf = 0; cf < 4; ++cf){
    const int co0 = (wc << 6) + (cf << 4) + (hi << 2);
    float bc[4];
    #pragma unroll
    for (int r = 0; r < 4; ++r) bc[r] = bcomb[(b << 7) + co0 + r];
    #pragma unroll
    for (int pf = 0; pf < 4; ++pf){
      #pragma unroll
      for (int r = 0; r < 4; ++r){
        ob[(size_t)(co0 + r) * 4096 + (h << 6) + (pf << 4) + l15] = acc[cf][pf][r] + bc[r];
      }
    }
  }
}

// ---------------------------------------------------------------------------
extern "C" void kernel_launch(void* const* d_in, const int* in_sizes, int n_in,
                              void* d_out, int out_size, void* d_ws, size_t ws_size,
                              hipStream_t stream)
{
  const float* x    = (const float*)d_in[0];
  const float* W    = (const float*)d_in[1];
  const float* bias = (const float*)d_in[2];
  const float* w1   = (const float*)d_in[3];
  const float* w2   = (const float*)d_in[4];
  const float* b2   = (const float*)d_in[5];
  float* out = (float*)d_out;

  char* ws = (char*)d_ws;
  float* part  = (float*)(ws);               // 262144 B
  float* attn  = (float*)(ws + 262144);      // 256 B
  float* bcomb = (float*)(ws + 262400);      // 8192 B
  u16*   xT    = (u16*)  (ws + 270592);      // 16 MB
  u16*   wcomb = (u16*)  (ws + 17047808);    // 4.7 MB

  xpose_pool<<<512, 256, 0, stream>>>(x, xT, part);
  attn_fc<<<16, 128, 0, stream>>>(part, w1, w2, b2, attn);
  combine<<<128, 256, 0, stream>>>(W, bias, attn, wcomb, bcomb);

  (void)hipFuncSetAttribute(reinterpret_cast<const void*>(conv_mfma),
                            hipFuncAttributeMaxDynamicSharedMemorySize, 67584);
  conv_mfma<<<512, 256, 67584, stream>>>(xT, wcomb, bcomb, out);
}